// Round 2
// baseline (83.872 us; speedup 1.0000x reference)
//
#include <hip/hip_runtime.h>
#include <stdint.h>

// TripletPromptEncoder: B=32768, D=512, V=32000, MAX_TOK=5
// Slot compaction (verified against reference einsum for all 4 cases):
//   tv, vv  -> [ts_tok, cp, ce, vp, ve]
//   tv, !vv -> [ts_tok, cp, ce, 0,  0 ]
//   !tv, vv -> [cp, ce, vp, ve, 0]
//   !tv,!vv -> [cp, ce, 0,  0,  0]
// where ts_tok = static_mask ? td*date_w+date_b : ts_token

#define DDIM 512
#define D4   128   // DDIM / 4
#define NTOK 5

static __device__ __forceinline__ float4 f4sel(bool p, float4 a, float4 b) {
    float4 r;
    r.x = p ? a.x : b.x;
    r.y = p ? a.y : b.y;
    r.z = p ? a.z : b.z;
    r.w = p ? a.w : b.w;
    return r;
}

static __device__ __forceinline__ float4 f4fma(float s, float4 w, float4 b) {
    float4 r;
    r.x = s * w.x + b.x;
    r.y = s * w.y + b.y;
    r.z = s * w.z + b.z;
    r.w = s * w.w + b.w;
    return r;
}

__global__ __launch_bounds__(256) void triplet_encoder_kernel(
    const float* __restrict__ code_table,
    const float* __restrict__ date_w,
    const float* __restrict__ date_b,
    const float* __restrict__ val_w,
    const float* __restrict__ val_b,
    const float* __restrict__ ts_token,
    const float* __restrict__ code_prefix,
    const float* __restrict__ val_prefix,
    const float* __restrict__ numerical_value,
    const float* __restrict__ time_delta_days,
    const int*   __restrict__ code,
    const int*   __restrict__ static_mask,          // bool passed as int32
    const int*   __restrict__ numerical_value_mask, // bool passed as int32
    float* __restrict__ out,
    int B)
{
    const int tid = threadIdx.x;
    const int d4 = tid & (D4 - 1);          // fixed vec4 position within D
    const int row_in_block = tid >> 7;      // 0..1 (256 threads / 128)
    const int rows_per_iter = gridDim.x * 2;

    // Small D-vectors: load once, keep in registers for the whole loop.
    const float4 dw = ((const float4*)date_w)[d4];
    const float4 db = ((const float4*)date_b)[d4];
    const float4 vw = ((const float4*)val_w)[d4];
    const float4 vb = ((const float4*)val_b)[d4];
    const float4 ts = ((const float4*)ts_token)[d4];
    const float4 cp = ((const float4*)code_prefix)[d4];
    const float4 vp = ((const float4*)val_prefix)[d4];
    const float4 z4 = make_float4(0.f, 0.f, 0.f, 0.f);

    for (int b = blockIdx.x * 2 + row_in_block; b < B; b += rows_per_iter) {
        const float td = time_delta_days[b];
        const float nv = numerical_value[b];
        const int   c  = code[b];
        const bool  sm = static_mask[b] != 0;
        const bool  vv = numerical_value_mask[b] != 0;
        const bool  tv = td != 0.0f;

        const float4 ce = ((const float4*)(code_table + (size_t)c * DDIM))[d4];

        const float4 te = f4fma(td, dw, db);   // time_emb
        const float4 ve = f4fma(nv, vw, vb);   // val_emb

        const float4 ts_tok = f4sel(sm, te, ts);        // used only when tv
        const float4 vpre   = f4sel(vv, vp, z4);        // val_prefix slot or 0
        const float4 vemb   = f4sel(vv, ve, z4);        // val_emb slot or 0

        // Compile-time slot indices; per-sample-uniform predicates.
        const float4 s0 = f4sel(tv, ts_tok, cp);
        const float4 s1 = f4sel(tv, cp, ce);
        const float4 s2 = f4sel(tv, ce, vpre);
        const float4 s3 = f4sel(tv, vpre, vemb);
        const float4 s4 = f4sel(tv, vemb, z4);

        float4* o = (float4*)(out + (size_t)b * (NTOK * DDIM)) + d4;
        o[0 * D4] = s0;
        o[1 * D4] = s1;
        o[2 * D4] = s2;
        o[3 * D4] = s3;
        o[4 * D4] = s4;
    }
}

extern "C" void kernel_launch(void* const* d_in, const int* in_sizes, int n_in,
                              void* d_out, int out_size, void* d_ws, size_t ws_size,
                              hipStream_t stream) {
    const float* code_table  = (const float*)d_in[0];
    const float* date_w      = (const float*)d_in[1];
    const float* date_b      = (const float*)d_in[2];
    const float* val_w       = (const float*)d_in[3];
    const float* val_b       = (const float*)d_in[4];
    const float* ts_token    = (const float*)d_in[5];
    const float* code_prefix = (const float*)d_in[6];
    const float* val_prefix  = (const float*)d_in[7];
    const float* num_val     = (const float*)d_in[8];
    const float* tdd         = (const float*)d_in[9];
    const int*   code        = (const int*)d_in[10];
    const int*   smask       = (const int*)d_in[11];
    const int*   nvmask      = (const int*)d_in[12];
    float* out = (float*)d_out;

    const int B = in_sizes[8];  // numerical_value has B elements

    // 2 samples per 256-thread block; cap grid at 2048 (256 CU x 8) and stride.
    int blocks_needed = (B + 1) / 2;
    int grid = blocks_needed < 2048 ? blocks_needed : 2048;

    triplet_encoder_kernel<<<grid, 256, 0, stream>>>(
        code_table, date_w, date_b, val_w, val_b, ts_token, code_prefix,
        val_prefix, num_val, tdd, code, smask, nvmask, out, B);
}

// Round 4
// 67.593 us; speedup vs baseline: 1.2408x; 1.2408x over previous
//
#include <hip/hip_runtime.h>
#include <stdint.h>

// TripletPromptEncoder: B=32768, D=512, V=32000, MAX_TOK=5
// Slot compaction (verified against reference einsum for all 4 cases):
//   tv, vv  -> [ts_tok, cp, ce, vp, ve]
//   tv, !vv -> [ts_tok, cp, ce, 0,  0 ]
//   !tv, vv -> [cp, ce, vp, ve, 0]
//   !tv,!vv -> [cp, ce, 0,  0,  0]
// where ts_tok = static_mask ? td*date_w+date_b : ts_token

#define DDIM 512
#define D4   128   // DDIM / 4
#define NTOK 5

// Native clang vector for nontemporal stores (HIP float4 is a class type,
// which __builtin_nontemporal_store rejects).
typedef float vf4 __attribute__((ext_vector_type(4)));

static __device__ __forceinline__ void nt_store(const float4& v, float4* p) {
    vf4 x;
    x.x = v.x; x.y = v.y; x.z = v.z; x.w = v.w;
    __builtin_nontemporal_store(x, (vf4*)p);
}

static __device__ __forceinline__ float4 f4sel(bool p, float4 a, float4 b) {
    float4 r;
    r.x = p ? a.x : b.x;
    r.y = p ? a.y : b.y;
    r.z = p ? a.z : b.z;
    r.w = p ? a.w : b.w;
    return r;
}

static __device__ __forceinline__ float4 f4fma(float s, float4 w, float4 b) {
    float4 r;
    r.x = s * w.x + b.x;
    r.y = s * w.y + b.y;
    r.z = s * w.z + b.z;
    r.w = s * w.w + b.w;
    return r;
}

__global__ __launch_bounds__(256) void triplet_encoder_kernel(
    const float* __restrict__ code_table,
    const float* __restrict__ date_w,
    const float* __restrict__ date_b,
    const float* __restrict__ val_w,
    const float* __restrict__ val_b,
    const float* __restrict__ ts_token,
    const float* __restrict__ code_prefix,
    const float* __restrict__ val_prefix,
    const float* __restrict__ numerical_value,
    const float* __restrict__ time_delta_days,
    const int*   __restrict__ code,
    const int*   __restrict__ static_mask,          // bool passed as int32
    const int*   __restrict__ numerical_value_mask, // bool passed as int32
    float* __restrict__ out,
    int B)
{
    const int tid = threadIdx.x;
    const int d4 = tid & (D4 - 1);          // fixed vec4 position within D
    const int row_in_block = tid >> 7;      // 0..1
    const int rows_per_iter = gridDim.x * 4;  // 2 rows/block x 2-sample unroll

    // Small D-vectors: load once, keep in registers for the whole loop.
    const float4 dw = ((const float4*)date_w)[d4];
    const float4 db = ((const float4*)date_b)[d4];
    const float4 vw = ((const float4*)val_w)[d4];
    const float4 vb = ((const float4*)val_b)[d4];
    const float4 ts = ((const float4*)ts_token)[d4];
    const float4 cp = ((const float4*)code_prefix)[d4];
    const float4 vp = ((const float4*)val_prefix)[d4];
    const float4 z4 = make_float4(0.f, 0.f, 0.f, 0.f);

    for (int b0 = blockIdx.x * 4 + row_in_block * 2; b0 < B; b0 += rows_per_iter) {
        const int b1 = b0 + 1;
        const bool have1 = (b1 < B);

        // ---- hoisted loads: two independent gather chains in flight ----
        const float td0 = time_delta_days[b0];
        const float nv0 = numerical_value[b0];
        const int   c0  = code[b0];
        const bool  sm0 = static_mask[b0] != 0;
        const bool  vv0 = numerical_value_mask[b0] != 0;
        const float4 ce0 = ((const float4*)(code_table + (size_t)c0 * DDIM))[d4];

        const int   bs1 = have1 ? b1 : b0;   // safe clamp (no-op when B%4==0)
        const float td1 = time_delta_days[bs1];
        const float nv1 = numerical_value[bs1];
        const int   c1  = code[bs1];
        const bool  sm1 = static_mask[bs1] != 0;
        const bool  vv1 = numerical_value_mask[bs1] != 0;
        const float4 ce1 = ((const float4*)(code_table + (size_t)c1 * DDIM))[d4];

        // ---- sample b0 ----
        {
            const bool tv = td0 != 0.0f;
            const float4 te = f4fma(td0, dw, db);
            const float4 ve = f4fma(nv0, vw, vb);
            const float4 ts_tok = f4sel(sm0, te, ts);
            const float4 vpre   = f4sel(vv0, vp, z4);
            const float4 vemb   = f4sel(vv0, ve, z4);
            const float4 s0 = f4sel(tv, ts_tok, cp);
            const float4 s1 = f4sel(tv, cp, ce0);
            const float4 s2 = f4sel(tv, ce0, vpre);
            const float4 s3 = f4sel(tv, vpre, vemb);
            const float4 s4 = f4sel(tv, vemb, z4);
            float4* o = (float4*)(out + (size_t)b0 * (NTOK * DDIM)) + d4;
            nt_store(s0, &o[0 * D4]);
            nt_store(s1, &o[1 * D4]);
            nt_store(s2, &o[2 * D4]);
            nt_store(s3, &o[3 * D4]);
            nt_store(s4, &o[4 * D4]);
        }

        // ---- sample b1 ----
        if (have1) {
            const bool tv = td1 != 0.0f;
            const float4 te = f4fma(td1, dw, db);
            const float4 ve = f4fma(nv1, vw, vb);
            const float4 ts_tok = f4sel(sm1, te, ts);
            const float4 vpre   = f4sel(vv1, vp, z4);
            const float4 vemb   = f4sel(vv1, ve, z4);
            const float4 s0 = f4sel(tv, ts_tok, cp);
            const float4 s1 = f4sel(tv, cp, ce1);
            const float4 s2 = f4sel(tv, ce1, vpre);
            const float4 s3 = f4sel(tv, vpre, vemb);
            const float4 s4 = f4sel(tv, vemb, z4);
            float4* o = (float4*)(out + (size_t)b1 * (NTOK * DDIM)) + d4;
            nt_store(s0, &o[0 * D4]);
            nt_store(s1, &o[1 * D4]);
            nt_store(s2, &o[2 * D4]);
            nt_store(s3, &o[3 * D4]);
            nt_store(s4, &o[4 * D4]);
        }
    }
}

extern "C" void kernel_launch(void* const* d_in, const int* in_sizes, int n_in,
                              void* d_out, int out_size, void* d_ws, size_t ws_size,
                              hipStream_t stream) {
    const float* code_table  = (const float*)d_in[0];
    const float* date_w      = (const float*)d_in[1];
    const float* date_b      = (const float*)d_in[2];
    const float* val_w       = (const float*)d_in[3];
    const float* val_b       = (const float*)d_in[4];
    const float* ts_token    = (const float*)d_in[5];
    const float* code_prefix = (const float*)d_in[6];
    const float* val_prefix  = (const float*)d_in[7];
    const float* num_val     = (const float*)d_in[8];
    const float* tdd         = (const float*)d_in[9];
    const int*   code        = (const int*)d_in[10];
    const int*   smask       = (const int*)d_in[11];
    const int*   nvmask      = (const int*)d_in[12];
    float* out = (float*)d_out;

    const int B = in_sizes[8];  // numerical_value has B elements

    // 4 samples per 256-thread block-iteration; cap grid at 2048 and stride.
    int blocks_needed = (B + 3) / 4;
    int grid = blocks_needed < 2048 ? blocks_needed : 2048;

    triplet_encoder_kernel<<<grid, 256, 0, stream>>>(
        code_table, date_w, date_b, val_w, val_b, ts_token, code_prefix,
        val_prefix, num_val, tdd, code, smask, nvmask, out, B);
}

// Round 5
// 67.201 us; speedup vs baseline: 1.2481x; 1.0058x over previous
//
#include <hip/hip_runtime.h>
#include <stdint.h>

// TripletPromptEncoder: B=32768, D=512, V=32000, MAX_TOK=5
// Slot compaction (verified against reference einsum for all 4 cases):
//   tv, vv  -> [ts_tok, cp, ce, vp, ve]
//   tv, !vv -> [ts_tok, cp, ce, 0,  0 ]
//   !tv, vv -> [cp, ce, vp, ve, 0]
//   !tv,!vv -> [cp, ce, 0,  0,  0]
// where ts_tok = static_mask ? td*date_w+date_b : ts_token

#define DDIM 512
#define D4   128   // DDIM / 4
#define NTOK 5
#define UNROLL 4   // samples per thread-row per iteration

// Native clang vector for nontemporal stores (HIP float4 is a class type,
// which __builtin_nontemporal_store rejects).
typedef float vf4 __attribute__((ext_vector_type(4)));

static __device__ __forceinline__ void nt_store(const float4& v, float4* p) {
    vf4 x;
    x.x = v.x; x.y = v.y; x.z = v.z; x.w = v.w;
    __builtin_nontemporal_store(x, (vf4*)p);
}

static __device__ __forceinline__ float4 f4sel(bool p, float4 a, float4 b) {
    float4 r;
    r.x = p ? a.x : b.x;
    r.y = p ? a.y : b.y;
    r.z = p ? a.z : b.z;
    r.w = p ? a.w : b.w;
    return r;
}

static __device__ __forceinline__ float4 f4fma(float s, float4 w, float4 b) {
    float4 r;
    r.x = s * w.x + b.x;
    r.y = s * w.y + b.y;
    r.z = s * w.z + b.z;
    r.w = s * w.w + b.w;
    return r;
}

__global__ __launch_bounds__(256) void triplet_encoder_kernel(
    const float* __restrict__ code_table,
    const float* __restrict__ date_w,
    const float* __restrict__ date_b,
    const float* __restrict__ val_w,
    const float* __restrict__ val_b,
    const float* __restrict__ ts_token,
    const float* __restrict__ code_prefix,
    const float* __restrict__ val_prefix,
    const float* __restrict__ numerical_value,
    const float* __restrict__ time_delta_days,
    const int*   __restrict__ code,
    const int*   __restrict__ static_mask,          // bool passed as int32
    const int*   __restrict__ numerical_value_mask, // bool passed as int32
    float* __restrict__ out,
    int B)
{
    const int tid = threadIdx.x;
    const int d4 = tid & (D4 - 1);          // fixed vec4 position within D
    const int row_in_block = tid >> 7;      // 0..1
    const int rows_per_iter = gridDim.x * 2 * UNROLL;

    // Small D-vectors: load once, keep in registers for the whole loop.
    const float4 dw = ((const float4*)date_w)[d4];
    const float4 db = ((const float4*)date_b)[d4];
    const float4 vw = ((const float4*)val_w)[d4];
    const float4 vb = ((const float4*)val_b)[d4];
    const float4 ts = ((const float4*)ts_token)[d4];
    const float4 cp = ((const float4*)code_prefix)[d4];
    const float4 vp = ((const float4*)val_prefix)[d4];
    const float4 z4 = make_float4(0.f, 0.f, 0.f, 0.f);

    for (int b0 = (blockIdx.x * 2 + row_in_block) * UNROLL; b0 < B;
         b0 += rows_per_iter) {

        // ---- issue ALL scalar loads + gathers first: 4 chains in flight ----
        float td[UNROLL], nv[UNROLL];
        int   cc[UNROLL];
        bool  sm[UNROLL], vv[UNROLL], ok[UNROLL];
        float4 ce[UNROLL];

#pragma unroll
        for (int u = 0; u < UNROLL; ++u) {
            const int b = b0 + u;
            ok[u] = (b < B);
            const int bs = ok[u] ? b : b0;
            td[u] = time_delta_days[bs];
            nv[u] = numerical_value[bs];
            cc[u] = code[bs];
            sm[u] = static_mask[bs] != 0;
            vv[u] = numerical_value_mask[bs] != 0;
        }
#pragma unroll
        for (int u = 0; u < UNROLL; ++u) {
            ce[u] = ((const float4*)(code_table + (size_t)cc[u] * DDIM))[d4];
        }

        // ---- compute + store each sample ----
#pragma unroll
        for (int u = 0; u < UNROLL; ++u) {
            if (!ok[u]) continue;
            const int b = b0 + u;
            const bool tv = td[u] != 0.0f;
            const float4 te = f4fma(td[u], dw, db);
            const float4 ve = f4fma(nv[u], vw, vb);
            const float4 ts_tok = f4sel(sm[u], te, ts);
            const float4 vpre   = f4sel(vv[u], vp, z4);
            const float4 vemb   = f4sel(vv[u], ve, z4);
            const float4 s0 = f4sel(tv, ts_tok, cp);
            const float4 s1 = f4sel(tv, cp, ce[u]);
            const float4 s2 = f4sel(tv, ce[u], vpre);
            const float4 s3 = f4sel(tv, vpre, vemb);
            const float4 s4 = f4sel(tv, vemb, z4);
            float4* o = (float4*)(out + (size_t)b * (NTOK * DDIM)) + d4;
            nt_store(s0, &o[0 * D4]);
            nt_store(s1, &o[1 * D4]);
            nt_store(s2, &o[2 * D4]);
            nt_store(s3, &o[3 * D4]);
            nt_store(s4, &o[4 * D4]);
        }
    }
}

extern "C" void kernel_launch(void* const* d_in, const int* in_sizes, int n_in,
                              void* d_out, int out_size, void* d_ws, size_t ws_size,
                              hipStream_t stream) {
    const float* code_table  = (const float*)d_in[0];
    const float* date_w      = (const float*)d_in[1];
    const float* date_b      = (const float*)d_in[2];
    const float* val_w       = (const float*)d_in[3];
    const float* val_b       = (const float*)d_in[4];
    const float* ts_token    = (const float*)d_in[5];
    const float* code_prefix = (const float*)d_in[6];
    const float* val_prefix  = (const float*)d_in[7];
    const float* num_val     = (const float*)d_in[8];
    const float* tdd         = (const float*)d_in[9];
    const int*   code        = (const int*)d_in[10];
    const int*   smask       = (const int*)d_in[11];
    const int*   nvmask      = (const int*)d_in[12];
    float* out = (float*)d_out;

    const int B = in_sizes[8];  // numerical_value has B elements

    // 8 samples per 256-thread block (2 row-groups x 4-sample unroll).
    int blocks_needed = (B + 2 * UNROLL - 1) / (2 * UNROLL);
    int grid = blocks_needed < 4096 ? blocks_needed : 4096;

    triplet_encoder_kernel<<<grid, 256, 0, stream>>>(
        code_table, date_w, date_b, val_w, val_b, ts_token, code_prefix,
        val_prefix, num_val, tdd, code, smask, nvmask, out, B);
}